// Round 9
// baseline (2217.261 us; speedup 1.0000x reference)
//
#include <hip/hip_runtime.h>
#include <stdint.h>

#define BATCH 8192
#define ADIM 128
#define HDIM 256
#define VDIM 64
#define NSTEP 20
#define TB 16
#define HSP 17   // h_s/c_s stride (floats): ODD -> lane-distributed b32 reads conflict-free
#define ASP 20   // attr_s stride: 16B-aligned rows for b128 staging reads

typedef union { float4 v; float f[4]; } F4;

// ---------------- Threefry-2x32 (exactly JAX's lowering) ----------------
__device__ __forceinline__ uint32_t rotl32(uint32_t x, uint32_t d) {
  return (x << d) | (x >> (32u - d));
}
__device__ __forceinline__ void tf4(uint32_t& x0, uint32_t& x1, int r0, int r1, int r2, int r3) {
  x0 += x1; x1 = rotl32(x1, r0); x1 ^= x0;
  x0 += x1; x1 = rotl32(x1, r1); x1 ^= x0;
  x0 += x1; x1 = rotl32(x1, r2); x1 ^= x0;
  x0 += x1; x1 = rotl32(x1, r3); x1 ^= x0;
}
__device__ __forceinline__ void threefry2x32(uint32_t k0, uint32_t k1, uint32_t x0, uint32_t x1,
                                             uint32_t& o0, uint32_t& o1) {
  uint32_t k2 = k0 ^ k1 ^ 0x1BD11BDAu;
  x0 += k0; x1 += k1;
  tf4(x0, x1, 13, 15, 26, 6);  x0 += k1; x1 += k2 + 1u;
  tf4(x0, x1, 17, 29, 16, 24); x0 += k2; x1 += k0 + 2u;
  tf4(x0, x1, 13, 15, 26, 6);  x0 += k0; x1 += k1 + 3u;
  tf4(x0, x1, 17, 29, 16, 24); x0 += k1; x1 += k2 + 4u;
  tf4(x0, x1, 13, 15, 26, 6);  x0 += k2; x1 += k0 + 5u;
  o0 = x0; o1 = x1;
}

__device__ __forceinline__ float sigm(float x) { return 1.0f / (1.0f + expf(-x)); }

// wave-uniform broadcast of lane t's value -> SGPR (feeds v_fma scalar slot)
__device__ __forceinline__ float bcast(float x, int t) {
  return __int_as_float(__builtin_amdgcn_readlane(__float_as_int(x), t));
}

// ---------------- prep: repack weights ----------------
// ws layout (floats): WhhT4[256][256][4] @0      (k, unit, gate)  1 MB
//                     WvT4 [64][64][4]   @262144 (k/4, v, k%4) -> b128 per 4 k
//                     WaT  [128][256]    @278528 (k, unit)
//                     WihT4[64][256][4]  @311296 (v, unit, gate)
__global__ void prep_kernel(const float* __restrict__ Whh, const float* __restrict__ Wv,
                            const float* __restrict__ Wa, const float* __restrict__ Wih,
                            float* __restrict__ ws) {
  int n = blockIdx.x * blockDim.x + threadIdx.x;
  int stride = gridDim.x * blockDim.x;
  float* WhhT4 = ws;
  float* WvT4  = ws + 262144;
  float* WaT   = ws + 278528;
  float* WihT4 = ws + 311296;
  for (int i = n; i < 256 * 1024; i += stride) {
    int k = i >> 10, rem = i & 1023, u = rem >> 2, g = rem & 3;
    WhhT4[i] = Whh[((g << 8) + u) * 256 + k];
  }
  for (int i = n; i < 64 * 64 * 4; i += stride) {
    int kg = i >> 8, v = (i >> 2) & 63, j = i & 3;
    WvT4[i] = Wv[v * 256 + (kg << 2) + j];
  }
  for (int i = n; i < 128 * 256; i += stride) { int k = i >> 8, uu = i & 255; WaT[i] = Wa[uu * 128 + k]; }
  for (int i = n; i < 64 * 1024; i += stride) {
    int v = i >> 10, rem = i & 1023, uu = rem >> 2, g = rem & 3;
    WihT4[i] = Wih[((g << 8) + uu) * 64 + v];
  }
}

// ---------------- main persistent kernel ----------------
// 512 blocks x 256 threads; block owns TB=16 samples for all 21 steps.
// R9 vs R1 (the proven-fastest structure): each thread now computes TWO units
// x EIGHT samples (wave pair {0,1} = samples 0-7, {2,3} = 8-15; wave w covers
// units (w&1)*128 + {lane, lane+64}). One readlane h-broadcast now feeds 8
// gate FMAs instead of 4 -> readlanes/thread/step 4096 -> 2048. WvT repacked
// so logit weights load b128 per 4 k (256 -> 64 loads). Gate FMA count
// unchanged; every accumulator's k-ascending chain and all values identical
// to R1 -> bit-exact. Cell state in LDS (c_s) keeps VGPR under the (256,2)
// 128 cap (R2/R6 spill lessons: watch WRITE_SIZE).
__global__ __launch_bounds__(256, 2) void sender_main(
    const float* __restrict__ attr, const float* __restrict__ b_a,
    const float* __restrict__ b_ih, const float* __restrict__ b_hh,
    const float* __restrict__ b_v,
    const float* __restrict__ WhhT4, const float* __restrict__ WvT4,
    const float* __restrict__ WaT, const float* __restrict__ WihT4,
    float* __restrict__ out) {
  __shared__ float h_s[HDIM][HSP];                    // h_s[k][phys sample]
  __shared__ float c_s[HDIM][HSP];                    // c_s[unit][phys sample]
  __shared__ __align__(16) float attr_s[ADIM][ASP];   // attr_s[k][sample]
  __shared__ float slp_s[TB], plp_s[TB], ep_s[TB];
  __shared__ int ch_s[TB];

  const int tid = threadIdx.x;
  const int w = tid >> 6;         // wave id
  const int lane = tid & 63;
  const int u = (w << 6) + lane;  // unit for h0/init step (1-unit mapping)
  const int w4 = w << 2;
  // 2-unit mapping for the 20 sampled steps:
  const int ug = (w & 1) << 7;    // unit group base: 0 or 128
  const int u0 = ug + lane;
  const int u1 = ug + 64 + lane;
  const int sg = (w >> 1) << 3;   // sample group base: 0 or 8
  const int rot = (w & 1) << 2;   // slot rotation within group: 0 or 4
  const int b0 = blockIdx.x * TB;

  if (tid < TB) { slp_s[tid] = 0.0f; plp_s[tid] = 0.0f; ep_s[tid] = 1.0f; }

  // ---- stage attr tile, transposed to k-major ----
  {
    int r = tid >> 5;            // 0..7
    int cm = (tid & 31) << 2;    // 0,4,...,124
    #pragma unroll
    for (int pass = 0; pass < 2; ++pass) {
      int row = r + (pass << 3);
      F4 vv; vv.v = *(const float4*)&attr[(size_t)(b0 + row) * ADIM + cm];
      attr_s[cm + 0][row] = vv.f[0];
      attr_s[cm + 1][row] = vv.f[1];
      attr_s[cm + 2][row] = vv.f[2];
      attr_s[cm + 3][row] = vv.f[3];
    }
  }
  __syncthreads();

  // ---- h0 = attr @ W_a^T + b_a (R1 verbatim: 1 unit x 16 samples) ----
  {
    float acc[16];
    #pragma unroll
    for (int s = 0; s < 16; ++s) acc[s] = 0.0f;
    #pragma unroll 2
    for (int k = 0; k < ADIM; ++k) {
      F4 a0, a1, a2, a3;
      a0.v = *(const float4*)&attr_s[k][0];
      a1.v = *(const float4*)&attr_s[k][4];
      a2.v = *(const float4*)&attr_s[k][8];
      a3.v = *(const float4*)&attr_s[k][12];
      float wa = WaT[(k << 8) + u];
      #pragma unroll
      for (int j = 0; j < 4; ++j) {
        acc[j]      = fmaf(a0.f[j], wa, acc[j]);
        acc[4 + j]  = fmaf(a1.f[j], wa, acc[4 + j]);
        acc[8 + j]  = fmaf(a2.f[j], wa, acc[8 + j]);
        acc[12 + j] = fmaf(a3.f[j], wa, acc[12 + j]);
      }
    }
    float ba = b_a[u];
    #pragma unroll
    for (int s = 0; s < 16; ++s) h_s[u][s] = acc[s] + ba;
  }
  __syncthreads();

  const float bv = b_v[lane];

  // ---- initial LSTM step, x = 0, c = 0 (R1 mapping; c -> LDS) ----
  {
    float bgi[4];
    #pragma unroll
    for (int g = 0; g < 4; ++g) bgi[g] = b_ih[(g << 8) + u] + b_hh[(g << 8) + u];
    float ga[16][4];
    #pragma unroll
    for (int s = 0; s < 16; ++s)
      #pragma unroll
      for (int g = 0; g < 4; ++g) ga[s][g] = 0.0f;
    #pragma unroll 1
    for (int kc = 0; kc < 16; ++kc) {
      const int k0 = kc << 4;
      const int kk = k0 + (lane & 15);
      float hch[16];
      #pragma unroll
      for (int s = 0; s < 16; ++s) hch[s] = h_s[kk][(s + w4) & 15];
      #pragma unroll
      for (int t = 0; t < 16; ++t) {
        const int k = k0 + t;
        F4 wv4; wv4.v = *(const float4*)&WhhT4[(k << 10) + (u << 2)];
        #pragma unroll
        for (int s = 0; s < 16; ++s) {
          float hb = bcast(hch[s], t);
          ga[s][0] = fmaf(hb, wv4.f[0], ga[s][0]);
          ga[s][1] = fmaf(hb, wv4.f[1], ga[s][1]);
          ga[s][2] = fmaf(hb, wv4.f[2], ga[s][2]);
          ga[s][3] = fmaf(hb, wv4.f[3], ga[s][3]);
        }
      }
    }
    __syncthreads();  // all reads of h_s done before overwrite
    #pragma unroll
    for (int s = 0; s < 16; ++s) {
      const int sp = (s + w4) & 15;
      float gi = ga[s][0] + bgi[0];
      float gf = ga[s][1] + bgi[1];
      float gg = ga[s][2] + bgi[2];
      float go = ga[s][3] + bgi[3];
      float cn = sigm(gf) * 0.0f + sigm(gi) * tanhf(gg);  // c starts at 0
      c_s[u][sp] = cn;
      h_s[u][sp] = sigm(go) * tanhf(cn);
    }
    __syncthreads();
  }

  // per-gate bias for the two owned units
  float bg0[4], bg1[4];
  #pragma unroll
  for (int g = 0; g < 4; ++g) {
    bg0[g] = b_ih[(g << 8) + u0] + b_hh[(g << 8) + u0];
    bg1[g] = b_ih[(g << 8) + u1] + b_hh[(g << 8) + u1];
  }

  // ---- 20 sampled steps ----
  #pragma unroll 1
  for (int l = 0; l < NSTEP; ++l) {
    uint32_t kl0, kl1;
    threefry2x32(0u, 42u, 0u, (uint32_t)l, kl0, kl1);

    const bool last = (l == NSTEP - 1);
    float la[4] = {0.0f, 0.0f, 0.0f, 0.0f};  // logits for phys samples 4w..4w+3, v=lane
    float ga0[8][4], ga1[8][4];              // [slot][gate] for u0, u1
    #pragma unroll
    for (int s = 0; s < 8; ++s)
      #pragma unroll
      for (int g = 0; g < 4; ++g) { ga0[s][g] = 0.0f; ga1[s][g] = 0.0f; }

    if (!last) {
      #pragma unroll 1
      for (int kc = 0; kc < 16; ++kc) {
        const int k0 = kc << 4;
        const int kk = k0 + (lane & 15);
        float hch[8];
        #pragma unroll
        for (int s = 0; s < 8; ++s) hch[s] = h_s[kk][sg + ((s + rot) & 7)];
        F4 wvv;
        #pragma unroll
        for (int t = 0; t < 16; ++t) {
          const int k = k0 + t;
          F4 wk0, wk1;
          wk0.v = *(const float4*)&WhhT4[(k << 10) + (u0 << 2)];
          wk1.v = *(const float4*)&WhhT4[(k << 10) + (u1 << 2)];
          if ((t & 3) == 0) wvv.v = *(const float4*)&WvT4[((k >> 2) << 8) + (lane << 2)];
          #pragma unroll
          for (int s = 0; s < 8; ++s) {
            float hb = bcast(hch[s], t);
            if (s < 4) la[s] = fmaf(hb, wvv.f[t & 3], la[s]);  // slots 0..3 = phys 4w..4w+3
            ga0[s][0] = fmaf(hb, wk0.f[0], ga0[s][0]);
            ga0[s][1] = fmaf(hb, wk0.f[1], ga0[s][1]);
            ga0[s][2] = fmaf(hb, wk0.f[2], ga0[s][2]);
            ga0[s][3] = fmaf(hb, wk0.f[3], ga0[s][3]);
            ga1[s][0] = fmaf(hb, wk1.f[0], ga1[s][0]);
            ga1[s][1] = fmaf(hb, wk1.f[1], ga1[s][1]);
            ga1[s][2] = fmaf(hb, wk1.f[2], ga1[s][2]);
            ga1[s][3] = fmaf(hb, wk1.f[3], ga1[s][3]);
          }
        }
      }
    } else {
      // logits only
      #pragma unroll 1
      for (int kc = 0; kc < 16; ++kc) {
        const int k0 = kc << 4;
        const int kk = k0 + (lane & 15);
        float hch[4];
        #pragma unroll
        for (int s = 0; s < 4; ++s) hch[s] = h_s[kk][sg + ((s + rot) & 7)];
        F4 wvv;
        #pragma unroll
        for (int t = 0; t < 16; ++t) {
          const int k = k0 + t;
          if ((t & 3) == 0) wvv.v = *(const float4*)&WvT4[((k >> 2) << 8) + (lane << 2)];
          #pragma unroll
          for (int s = 0; s < 4; ++s) la[s] = fmaf(bcast(hch[s], t), wvv.f[t & 3], la[s]);
        }
      }
    }

    // ---- sampling: wave w handles phys samples 4w..4w+3 (= sg+rot+db); lane = vocab ----
    #pragma unroll
    for (int db = 0; db < 4; ++db) {
      float x = la[db] + bv;  // logits = h@W_v^T + b_v
      float m = x;
      #pragma unroll
      for (int o = 32; o > 0; o >>= 1) m = fmaxf(m, __shfl_xor(m, o));
      float e = expf(x - m);
      float s = e;
      #pragma unroll
      for (int o = 32; o > 0; o >>= 1) s += __shfl_xor(s, o);
      float lse = logf(s);
      float logp = x - m - lse;
      float p = expf(logp);
      float pe = p * logp;
      #pragma unroll
      for (int o = 32; o > 0; o >>= 1) pe += __shfl_xor(pe, o);
      uint32_t idx = ((uint32_t)(b0 + w4 + db) << 6) | (uint32_t)lane;
      uint32_t r0, r1;
      threefry2x32(kl0, kl1, 0u, idx, r0, r1);
      uint32_t bits = r0 ^ r1;
      float f01 = __uint_as_float((bits >> 9) | 0x3f800000u) - 1.0f;
      const float TINY = 1.17549435e-38f;
      float uu2 = fmaxf(TINY, f01 + TINY);
      float gn = -logf(-logf(uu2));
      float y = gn + x;
      float by = y; int bi = lane;
      #pragma unroll
      for (int o = 32; o > 0; o >>= 1) {
        float oy = __shfl_xor(by, o);
        int oi = __shfl_xor(bi, o);
        if (oy > by || (oy == by && oi < bi)) { by = oy; bi = oi; }
      }
      float lp = __shfl(logp, bi, 64);
      if (lane == 0) {
        int bb = w4 + db;
        ch_s[bb] = bi;
        slp_s[bb] += lp;
        plp_s[bb] += pe;
        ep_s[bb] *= expf(lp);
        out[(size_t)(b0 + bb) * NSTEP + l] = (float)bi;
      }
    }

    if (!last) {
      __syncthreads();  // everyone finished reading h_s; ch_s visible
      #pragma unroll
      for (int s = 0; s < 8; ++s) {
        const int sp = sg + ((s + rot) & 7);  // physical sample for this slot
        const int ch = ch_s[sp];
        F4 wi0, wi1;
        wi0.v = *(const float4*)&WihT4[(ch << 10) + (u0 << 2)];
        wi1.v = *(const float4*)&WihT4[(ch << 10) + (u1 << 2)];
        {
          float cr = c_s[u0][sp];
          float gi = ga0[s][0] + wi0.f[0] + bg0[0];
          float gf = ga0[s][1] + wi0.f[1] + bg0[1];
          float gg = ga0[s][2] + wi0.f[2] + bg0[2];
          float go = ga0[s][3] + wi0.f[3] + bg0[3];
          float cn = sigm(gf) * cr + sigm(gi) * tanhf(gg);
          c_s[u0][sp] = cn;
          h_s[u0][sp] = sigm(go) * tanhf(cn);
        }
        {
          float cr = c_s[u1][sp];
          float gi = ga1[s][0] + wi1.f[0] + bg1[0];
          float gf = ga1[s][1] + wi1.f[1] + bg1[1];
          float gg = ga1[s][2] + wi1.f[2] + bg1[2];
          float go = ga1[s][3] + wi1.f[3] + bg1[3];
          float cn = sigm(gf) * cr + sigm(gi) * tanhf(gg);
          c_s[u1][sp] = cn;
          h_s[u1][sp] = sigm(go) * tanhf(cn);
        }
      }
      __syncthreads();
    }
  }

  __syncthreads();
  if (tid < TB) {
    int bb = b0 + tid;
    out[(size_t)BATCH * NSTEP + bb]             = slp_s[tid];
    out[(size_t)BATCH * NSTEP + BATCH + bb]     = plp_s[tid];
    out[(size_t)BATCH * NSTEP + 2 * BATCH + bb] = ep_s[tid];
  }
}

extern "C" void kernel_launch(void* const* d_in, const int* in_sizes, int n_in,
                              void* d_out, int out_size, void* d_ws, size_t ws_size,
                              hipStream_t stream) {
  // setup_inputs order:
  // 0 attrVector [8192,128], 1 W_a [256,128], 2 b_a [256], 3 W_ih [1024,64],
  // 4 W_hh [1024,256], 5 b_ih [1024], 6 b_hh [1024], 7 W_v [64,256], 8 b_v [64]
  const float* attr = (const float*)d_in[0];
  const float* W_a  = (const float*)d_in[1];
  const float* b_a  = (const float*)d_in[2];
  const float* W_ih = (const float*)d_in[3];
  const float* W_hh = (const float*)d_in[4];
  const float* b_ih = (const float*)d_in[5];
  const float* b_hh = (const float*)d_in[6];
  const float* W_v  = (const float*)d_in[7];
  const float* b_v  = (const float*)d_in[8];
  float* ws = (float*)d_ws;

  prep_kernel<<<256, 256, 0, stream>>>(W_hh, W_v, W_a, W_ih, ws);
  sender_main<<<BATCH / TB, 256, 0, stream>>>(
      attr, b_a, b_ih, b_hh, b_v,
      ws, ws + 262144, ws + 278528, ws + 311296,
      (float*)d_out);
}